// Round 3
// baseline (1679.931 us; speedup 1.0000x reference)
//
#include <hip/hip_runtime.h>
#include <hip/hip_bf16.h>
#include <math.h>

// Problem constants
constexpr int cB   = 2;
constexpr int cS   = 2048;
constexpr int cD   = 1024;
constexpr int cQH  = 16;
constexpr int cKVH = 4;
constexpr int cDH  = 64;
constexpr int cTOPK = 128;
constexpr int cM   = cB * cS;          // 4096 rows for all GEMMs
constexpr int cNB  = cS / 64;          // 32 j-blocks of 64
constexpr int cLSZ = 384;              // kept-list capacity (128 + tie slack)

// ---------------------------------------------------------------------------
// GEMM: C[m][n] = sum_k A[m*K+k] * W[n*K+k]   (A @ W^T), fp32 tiled.
// ---------------------------------------------------------------------------
__global__ __launch_bounds__(256) void gemm_xwT(const float* __restrict__ A,
                                                const float* __restrict__ W,
                                                float* __restrict__ C,
                                                int M, int N, int K) {
    __shared__ float As[16][64 + 1];
    __shared__ float Ws[16][64 + 1];
    const int tid = threadIdx.x;
    const int tx = tid & 15;
    const int ty = tid >> 4;
    const int m0 = blockIdx.y * 64;
    const int n0 = blockIdx.x * 64;

    float acc[4][4] = {};
    const int lrow = tid >> 2;
    const int lkk  = (tid & 3) * 4;

    for (int k0 = 0; k0 < K; k0 += 16) {
        const float4 a4 = *(const float4*)(A + (size_t)(m0 + lrow) * K + k0 + lkk);
        As[lkk + 0][lrow] = a4.x;
        As[lkk + 1][lrow] = a4.y;
        As[lkk + 2][lrow] = a4.z;
        As[lkk + 3][lrow] = a4.w;
        const float4 w4 = *(const float4*)(W + (size_t)(n0 + lrow) * K + k0 + lkk);
        Ws[lkk + 0][lrow] = w4.x;
        Ws[lkk + 1][lrow] = w4.y;
        Ws[lkk + 2][lrow] = w4.z;
        Ws[lkk + 3][lrow] = w4.w;
        __syncthreads();

        #pragma unroll
        for (int kk = 0; kk < 16; ++kk) {
            float a[4], w[4];
            #pragma unroll
            for (int x = 0; x < 4; ++x) a[x] = As[kk][ty * 4 + x];
            #pragma unroll
            for (int x = 0; x < 4; ++x) w[x] = Ws[kk][tx * 4 + x];
            #pragma unroll
            for (int y = 0; y < 4; ++y)
                #pragma unroll
                for (int x = 0; x < 4; ++x)
                    acc[y][x] += a[y] * w[x];
        }
        __syncthreads();
    }

    #pragma unroll
    for (int y = 0; y < 4; ++y) {
        const int m = m0 + ty * 4 + y;
        float4 r = make_float4(acc[y][0], acc[y][1], acc[y][2], acc[y][3]);
        *(float4*)(C + (size_t)m * N + n0 + tx * 4) = r;
    }
}

// ---------------------------------------------------------------------------
// RoPE in place. buf layout: (B*S, H, DH) row-major. Half-split rotation.
// ---------------------------------------------------------------------------
__global__ void rope_kernel(float* __restrict__ buf, int H, int total) {
    int idx = blockIdx.x * blockDim.x + threadIdx.x;
    if (idx >= total) return;
    const int d   = idx & 31;
    const int h   = (idx >> 5) % H;
    const int row = idx / (32 * H);
    const int s   = row % cS;
    const float inv_freq = powf(10000.0f, -(float)d / 32.0f);
    const float ang = (float)s * inv_freq;
    const float c  = cosf(ang);
    const float si = sinf(ang);
    float* p = buf + (size_t)row * H * cDH + (size_t)h * cDH;
    const float x1 = p[d];
    const float x2 = p[d + 32];
    p[d]      = x1 * c - x2 * si;
    p[d + 32] = x2 * c + x1 * si;
}

// ---------------------------------------------------------------------------
// Order-preserving float <-> uint bit maps (no NaNs here).
// ---------------------------------------------------------------------------
__device__ inline unsigned fmap(float f) {
    unsigned u = __float_as_uint(f);
    return (u & 0x80000000u) ? ~u : (u | 0x80000000u);
}
__device__ inline float funmap(unsigned u) {
    unsigned v = (u & 0x80000000u) ? (u & 0x7FFFFFFFu) : ~u;
    return __uint_as_float(v);
}

// ---------------------------------------------------------------------------
// Attention with exact top-k threshold.
// Block = 512 threads = 8 waves = 2 consecutive i  x  4 q-heads of one kvh.
// k-tiles (64 rows) staged in LDS once per block, shared by all 8 waves.
// q (B,S,QH,DH), k/v (B,S,KVH,DH), out (B,S,QH,DH) all fp32.
// ---------------------------------------------------------------------------
__global__ __launch_bounds__(512) void attn_wave_kernel(
        const float* __restrict__ q, const float* __restrict__ k,
        const float* __restrict__ v, float* __restrict__ out) {
    __shared__ float    kt[64][68];       // k-tile, +16B row pad (bank partition)
    __shared__ unsigned klist[8][cLSZ];   // keys, later overwritten by weights
    __shared__ int      jlist[8][cLSZ];

    const int tid  = threadIdx.x;
    const int lane = tid & 63;
    const int w    = tid >> 6;            // 0..7

    // block decode: bid -> (b, kvh, i0); consecutive bids step i0 (L2 reuse)
    const int bid = blockIdx.x;
    const int i0  = (bid & 1023) * 2;
    const int grp = bid >> 10;            // 0..7
    const int kvh = grp & 3;
    const int b   = grp >> 2;

    // wave decode: waves 0-3 -> i0, waves 4-7 -> i0+1; h = kvh*4 + (w&3)
    const int i = __builtin_amdgcn_readfirstlane(i0 + (w >> 2));
    const int h = __builtin_amdgcn_readfirstlane(kvh * 4 + (w & 3));
    const int nb = (i0 >> 6) + 1;         // (i0+1)>>6 == i0>>6 (i0 even)

    const int g  = lane >> 2;             // j-row group within 16
    const int cq = lane & 3;              // 16B chunk id

    // q chunks for this lane: chunk (t*4 + cq), t = 0..3
    const float4* qv = (const float4*)(q + ((size_t)(b * cS + i) * cQH + h) * cDH);
    float4 qreg[4];
    #pragma unroll
    for (int t = 0; t < 4; ++t) qreg[t] = qv[t * 4 + cq];

    const size_t bS = (size_t)b * cS;

    // staging assignment: each thread loads 2 float4 chunks of the k-tile
    const int srow = tid >> 3;            // 0..63
    const int sc8  = tid & 7;             // 0..7

    // --- scores -> per-lane uint keys (key[jb] is score of j = jb*64+lane) -
    unsigned key[cNB];
    #pragma unroll 1
    for (int jb = 0; jb < cNB; ++jb) {
        if (jb >= nb) { key[jb] = 0u; continue; }

        // stage k rows [jb*64, jb*64+64) into LDS (all 512 threads)
        #pragma unroll
        for (int t = 0; t < 2; ++t) {
            const int chunk = sc8 + 8 * t;            // 0..15
            const int j = (jb << 6) + srow;
            const float4 kv4 = *(const float4*)(
                k + ((size_t)(bS + j) * cKVH + kvh) * cDH + chunk * 4);
            *(float4*)&kt[srow][chunk * 4] = kv4;
        }
        __syncthreads();

        unsigned kreg = 0u;
        #pragma unroll
        for (int u = 0; u < 4; ++u) {
            const int jr = (u << 4) + g;              // k-tile row this lane dots
            float acc = 0.f;
            #pragma unroll
            for (int t = 0; t < 4; ++t) {
                const float4 k4 = *(const float4*)&kt[jr][(t * 4 + cq) * 4];
                const float4 q4 = qreg[t];
                acc += q4.x * k4.x + q4.y * k4.y + q4.z * k4.z + q4.w * k4.w;
            }
            acc += __shfl_xor(acc, 1);
            acc += __shfl_xor(acc, 2);
            const float sv = __shfl(acc, (lane & 15) << 2);
            if ((lane >> 4) == u) {
                const int jm = (jb << 6) + lane;
                kreg = (jm <= i) ? fmap(sv * 0.125f) : 0u;
            }
        }
        key[jb] = kreg;
        __syncthreads();    // before next stage overwrites kt
    }

    // --- row max (uint max == float max under the order map) ---------------
    unsigned um = 0u;
    #pragma unroll
    for (int jb = 0; jb < cNB; ++jb) um = max(um, key[jb]);
    #pragma unroll
    for (int off = 32; off >= 1; off >>= 1)
        um = max(um, (unsigned)__shfl_xor((int)um, off));
    const float mrow = funmap(um);

    // --- exact 128th-largest key via bisection on uint space ---------------
    unsigned lo = 0u, hi = 0xFFFFFFFFu;
    while (lo < hi) {
        const unsigned d   = hi - lo;
        const unsigned mid = lo + (d >> 1) + (d & 1u);
        int c = 0;
        #pragma unroll
        for (int jb = 0; jb < cNB; ++jb) {
            if (jb >= nb) break;
            c += __popcll(__ballot(key[jb] >= mid));
        }
        if (c >= cTOPK) lo = mid; else hi = mid - 1u;
    }
    const unsigned ustar = lo;   // 0 when fewer than TOPK valid -> keep all

    // --- ballot-prefix compaction of kept (j, key) into LDS ----------------
    const unsigned long long mlt = (1ull << lane) - 1ull;
    int base = 0;
    #pragma unroll
    for (int jb = 0; jb < cNB; ++jb) {
        if (jb >= nb) break;
        const int j = (jb << 6) + lane;
        const bool keep = (j <= i) && (key[jb] >= ustar);
        const unsigned long long mk = __ballot(keep);
        const int pos = base + __popcll(mk & mlt);
        if (keep && pos < cLSZ) { klist[w][pos] = key[jb]; jlist[w][pos] = j; }
        base += __popcll(mk);
    }
    const int cnt = min(base, cLSZ);

    // --- weights + Z (overwrite keys with weights in place) ----------------
    float zp = 0.f;
    for (int t = lane; t < cnt; t += 64) {
        const float s  = funmap(klist[w][t]);
        const float wt = __expf(s - mrow);
        ((float*)klist[w])[t] = wt;
        zp += wt;
    }
    #pragma unroll
    for (int off = 32; off >= 1; off >>= 1) zp += __shfl_xor(zp, off);
    const float invZ = 1.0f / zp;

    // --- PV: lane = d, broadcast (w, j) from LDS, coalesced v rows ---------
    float acc = 0.f;
    #pragma unroll 4
    for (int t = 0; t < cnt; ++t) {
        const float wt = ((float*)klist[w])[t];
        const int   j  = jlist[w][t];
        acc += wt * v[((size_t)(bS + j) * cKVH + kvh) * cDH + lane];
    }
    out[((size_t)(bS + i) * cQH + h) * cDH + lane] = acc * invZ;
}

// ---------------------------------------------------------------------------
// Launch
// ---------------------------------------------------------------------------
extern "C" void kernel_launch(void* const* d_in, const int* in_sizes, int n_in,
                              void* d_out, int out_size, void* d_ws, size_t ws_size,
                              hipStream_t stream) {
    const float* x  = (const float*)d_in[0];
    const float* Wq = (const float*)d_in[1];
    const float* Wk = (const float*)d_in[2];
    const float* Wv = (const float*)d_in[3];
    const float* Wo = (const float*)d_in[4];
    float* out = (float*)d_out;

    float* ws = (float*)d_ws;
    float* qb = ws;                                   // (B,S,QH,DH)
    float* kb = qb + (size_t)cM * cQH * cDH;          // (B,S,KVH,DH)
    float* vb = kb + (size_t)cM * cKVH * cDH;         // (B,S,KVH,DH)
    float* ab = vb + (size_t)cM * cKVH * cDH;         // (B,S,QH,DH)

    dim3 blk(256);

    gemm_xwT<<<dim3((cQH * cDH) / 64, cM / 64), blk, 0, stream>>>(x, Wq, qb, cM, cQH * cDH, cD);
    gemm_xwT<<<dim3((cKVH * cDH) / 64, cM / 64), blk, 0, stream>>>(x, Wk, kb, cM, cKVH * cDH, cD);
    gemm_xwT<<<dim3((cKVH * cDH) / 64, cM / 64), blk, 0, stream>>>(x, Wv, vb, cM, cKVH * cDH, cD);

    {
        int totq = cM * cQH * 32;
        int totk = cM * cKVH * 32;
        rope_kernel<<<(totq + 255) / 256, blk, 0, stream>>>(qb, cQH, totq);
        rope_kernel<<<(totk + 255) / 256, blk, 0, stream>>>(kb, cKVH, totk);
    }

    attn_wave_kernel<<<(cB * cKVH * cS) / 2, dim3(512), 0, stream>>>(qb, kb, vb, ab);

    gemm_xwT<<<dim3(cD / 64, cM / 64), blk, 0, stream>>>(ab, Wo, out, cM, cD, cD);
}

// Round 4
// 1005.661 us; speedup vs baseline: 1.6705x; 1.6705x over previous
//
#include <hip/hip_runtime.h>
#include <hip/hip_bf16.h>
#include <math.h>

// Problem constants
constexpr int cB   = 2;
constexpr int cS   = 2048;
constexpr int cD   = 1024;
constexpr int cQH  = 16;
constexpr int cKVH = 4;
constexpr int cDH  = 64;
constexpr int cTOPK = 128;
constexpr int cM   = cB * cS;          // 4096 rows for all GEMMs
constexpr int cNB  = cS / 64;          // 32 j-blocks of 64
constexpr int cLSZ = 384;              // kept-list capacity (128 + tie slack)

typedef __attribute__((ext_vector_type(8))) short short8;
typedef __attribute__((ext_vector_type(4))) float floatx4;

// fp32 -> bf16 round-to-nearest-even (no NaN inputs in this problem)
__device__ inline ushort f2bf(float f) {
    unsigned u = __float_as_uint(f);
    return (ushort)((u + 0x7FFFu + ((u >> 16) & 1u)) >> 16);
}

// ---------------------------------------------------------------------------
// Cast fp32 -> bf16 (raw ushort), n multiple of 4.
// ---------------------------------------------------------------------------
__global__ void cast_f32_bf16(const float* __restrict__ src,
                              ushort* __restrict__ dst, int n) {
    int i4 = (blockIdx.x * blockDim.x + threadIdx.x) * 4;
    if (i4 >= n) return;
    const float4 v = *(const float4*)(src + i4);
    ushort4 r;
    r.x = f2bf(v.x); r.y = f2bf(v.y); r.z = f2bf(v.z); r.w = f2bf(v.w);
    *(ushort4*)(dst + i4) = r;
}

// ---------------------------------------------------------------------------
// MFMA bf16 GEMM: C[m][n] = sum_k A[m][k] * W[n][k]  (A @ W^T).
// A: M x K bf16 row-major, W: N x K bf16 row-major, C: M x N fp32.
// 128x128 block tile, BK=32, 256 threads = 4 waves (2x2 of 64x64).
// LDS k-outer layout [quad][row][8] -> lane-linear ds_read_b128.
// ---------------------------------------------------------------------------
__global__ __launch_bounds__(256) void gemm_bf16_bt(
        const ushort* __restrict__ A, const ushort* __restrict__ W,
        float* __restrict__ C, int M, int N, int K) {
    __shared__ short As[4][128][8];
    __shared__ short Bs[4][128][8];

    const int tid  = threadIdx.x;
    const int lane = tid & 63;
    const int w    = tid >> 6;          // 0..3
    const int wm   = (w & 1) * 64;
    const int wn   = (w >> 1) * 64;
    const int m0   = blockIdx.y * 128;
    const int n0   = blockIdx.x * 128;

    const int quad = lane >> 4;
    const int l16  = lane & 15;

    floatx4 acc[4][4];
    #pragma unroll
    for (int mi = 0; mi < 4; ++mi)
        #pragma unroll
        for (int ni = 0; ni < 4; ++ni)
            acc[mi][ni] = (floatx4){0.f, 0.f, 0.f, 0.f};

    const int sr = tid >> 1;            // staging row 0..127
    const int sh = (tid & 1) * 2;       // k-chunk pair 0 or 2

    for (int k0 = 0; k0 < K; k0 += 32) {
        const ushort* sa = A + (size_t)(m0 + sr) * K + k0 + sh * 8;
        const short8 a0 = *(const short8*)sa;
        const short8 a1 = *(const short8*)(sa + 8);
        const ushort* sw = W + (size_t)(n0 + sr) * K + k0 + sh * 8;
        const short8 b0 = *(const short8*)sw;
        const short8 b1 = *(const short8*)(sw + 8);
        *(short8*)&As[sh][sr][0]     = a0;
        *(short8*)&As[sh + 1][sr][0] = a1;
        *(short8*)&Bs[sh][sr][0]     = b0;
        *(short8*)&Bs[sh + 1][sr][0] = b1;
        __syncthreads();

        short8 af[4], bf[4];
        #pragma unroll
        for (int mi = 0; mi < 4; ++mi)
            af[mi] = *(const short8*)&As[quad][wm + mi * 16 + l16][0];
        #pragma unroll
        for (int ni = 0; ni < 4; ++ni)
            bf[ni] = *(const short8*)&Bs[quad][wn + ni * 16 + l16][0];
        #pragma unroll
        for (int mi = 0; mi < 4; ++mi)
            #pragma unroll
            for (int ni = 0; ni < 4; ++ni)
                acc[mi][ni] = __builtin_amdgcn_mfma_f32_16x16x32_bf16(
                    af[mi], bf[ni], acc[mi][ni], 0, 0, 0);
        __syncthreads();
    }

    // D layout: col = lane&15, row = quad*4 + reg
    #pragma unroll
    for (int mi = 0; mi < 4; ++mi)
        #pragma unroll
        for (int ni = 0; ni < 4; ++ni)
            #pragma unroll
            for (int r = 0; r < 4; ++r) {
                const int row = m0 + wm + mi * 16 + quad * 4 + r;
                const int col = n0 + wn + ni * 16 + l16;
                C[(size_t)row * N + col] = acc[mi][ni][r];
            }
}

// ---------------------------------------------------------------------------
// RoPE in place. buf layout: (B*S, H, DH) row-major fp32. Half-split rotation.
// ---------------------------------------------------------------------------
__global__ void rope_kernel(float* __restrict__ buf, int H, int total) {
    int idx = blockIdx.x * blockDim.x + threadIdx.x;
    if (idx >= total) return;
    const int d   = idx & 31;
    const int h   = (idx >> 5) % H;
    const int row = idx / (32 * H);
    const int s   = row % cS;
    const float inv_freq = powf(10000.0f, -(float)d / 32.0f);
    const float ang = (float)s * inv_freq;
    const float c  = cosf(ang);
    const float si = sinf(ang);
    float* p = buf + (size_t)row * H * cDH + (size_t)h * cDH;
    const float x1 = p[d];
    const float x2 = p[d + 32];
    p[d]      = x1 * c - x2 * si;
    p[d + 32] = x2 * c + x1 * si;
}

// ---------------------------------------------------------------------------
// Order-preserving float <-> uint bit maps (no NaNs here).
// ---------------------------------------------------------------------------
__device__ inline unsigned fmap(float f) {
    unsigned u = __float_as_uint(f);
    return (u & 0x80000000u) ? ~u : (u | 0x80000000u);
}
__device__ inline float funmap(unsigned u) {
    unsigned v = (u & 0x80000000u) ? (u & 0x7FFFFFFFu) : ~u;
    return __uint_as_float(v);
}

// ---------------------------------------------------------------------------
// Wave-per-row attention with exact top-k threshold (R2 structure, proven).
// Block = 256 threads = 4 waves = 4 query rows. Output written as bf16.
// q (B,S,QH,DH), k/v (B,S,KVH,DH) fp32; out (B,S,QH,DH) bf16.
// ---------------------------------------------------------------------------
__global__ __launch_bounds__(256) void attn_wave_kernel(
        const float* __restrict__ q, const float* __restrict__ k,
        const float* __restrict__ v, ushort* __restrict__ out) {
    __shared__ unsigned klist[4][cLSZ];   // keys, later overwritten by weights
    __shared__ int      jlist[4][cLSZ];

    const int lane = threadIdx.x & 63;
    const int w    = threadIdx.x >> 6;
    const int gid  = blockIdx.x * 4 + w;

    const int i   = __builtin_amdgcn_readfirstlane(gid % cS);
    const int h   = __builtin_amdgcn_readfirstlane((gid / cS) % cQH);
    const int b   = __builtin_amdgcn_readfirstlane(gid / (cS * cQH));
    const int kvh = h / (cQH / cKVH);
    const int nb  = (i >> 6) + 1;

    const int g  = lane >> 2;
    const int cq = lane & 3;

    const float4* qv = (const float4*)(q + ((size_t)(b * cS + i) * cQH + h) * cDH);
    float4 qreg[4];
    #pragma unroll
    for (int t = 0; t < 4; ++t) qreg[t] = qv[t * 4 + cq];

    const float4* kvec = (const float4*)k;
    const size_t  bS   = (size_t)b * cS;

    // --- scores -> per-lane uint keys (key[jb] is score of j = jb*64+lane) -
    unsigned key[cNB];
    #pragma unroll
    for (int jb = 0; jb < cNB; ++jb) {
        unsigned kreg = 0u;
        if (jb < nb) {
            #pragma unroll
            for (int u = 0; u < 4; ++u) {
                const int j = (jb << 6) + (u << 4) + g;
                const float4* kp = kvec + ((size_t)(bS + j) * cKVH + kvh) * 16;
                float acc = 0.f;
                #pragma unroll
                for (int t = 0; t < 4; ++t) {
                    const float4 k4 = kp[t * 4 + cq];
                    const float4 q4 = qreg[t];
                    acc += q4.x * k4.x + q4.y * k4.y + q4.z * k4.z + q4.w * k4.w;
                }
                acc += __shfl_xor(acc, 1);
                acc += __shfl_xor(acc, 2);
                const float sv = __shfl(acc, (lane & 15) << 2);
                if ((lane >> 4) == u) {
                    const int jm = (jb << 6) + lane;
                    kreg = (jm <= i) ? fmap(sv * 0.125f) : 0u;
                }
            }
        }
        key[jb] = kreg;
    }

    // --- row max ------------------------------------------------------------
    unsigned um = 0u;
    #pragma unroll
    for (int jb = 0; jb < cNB; ++jb) um = max(um, key[jb]);
    #pragma unroll
    for (int off = 32; off >= 1; off >>= 1)
        um = max(um, (unsigned)__shfl_xor((int)um, off));
    const float mrow = funmap(um);

    // --- exact 128th-largest key via bisection on uint space ----------------
    unsigned lo = 0u, hi = 0xFFFFFFFFu;
    while (lo < hi) {
        const unsigned d   = hi - lo;
        const unsigned mid = lo + (d >> 1) + (d & 1u);
        int c = 0;
        #pragma unroll
        for (int jb = 0; jb < cNB; ++jb) {
            if (jb >= nb) break;
            c += __popcll(__ballot(key[jb] >= mid));
        }
        if (c >= cTOPK) lo = mid; else hi = mid - 1u;
    }
    const unsigned ustar = lo;

    // --- ballot-prefix compaction of kept (j, key) into LDS -----------------
    const unsigned long long mlt = (1ull << lane) - 1ull;
    int base = 0;
    #pragma unroll
    for (int jb = 0; jb < cNB; ++jb) {
        if (jb >= nb) break;
        const int j = (jb << 6) + lane;
        const bool keep = (j <= i) && (key[jb] >= ustar);
        const unsigned long long mk = __ballot(keep);
        const int pos = base + __popcll(mk & mlt);
        if (keep && pos < cLSZ) { klist[w][pos] = key[jb]; jlist[w][pos] = j; }
        base += __popcll(mk);
    }
    const int cnt = min(base, cLSZ);

    // --- weights + Z --------------------------------------------------------
    float zp = 0.f;
    for (int t = lane; t < cnt; t += 64) {
        const float s  = funmap(klist[w][t]);
        const float wt = __expf(s - mrow);
        ((float*)klist[w])[t] = wt;
        zp += wt;
    }
    #pragma unroll
    for (int off = 32; off >= 1; off >>= 1) zp += __shfl_xor(zp, off);
    const float invZ = 1.0f / zp;

    // --- PV: lane = d --------------------------------------------------------
    float acc = 0.f;
    #pragma unroll 4
    for (int t = 0; t < cnt; ++t) {
        const float wt = ((float*)klist[w])[t];
        const int   j  = jlist[w][t];
        acc += wt * v[((size_t)(bS + j) * cKVH + kvh) * cDH + lane];
    }
    out[((size_t)(bS + i) * cQH + h) * cDH + lane] = f2bf(acc * invZ);
}

// ---------------------------------------------------------------------------
// Launch
// ---------------------------------------------------------------------------
extern "C" void kernel_launch(void* const* d_in, const int* in_sizes, int n_in,
                              void* d_out, int out_size, void* d_ws, size_t ws_size,
                              hipStream_t stream) {
    const float* x  = (const float*)d_in[0];
    const float* Wq = (const float*)d_in[1];
    const float* Wk = (const float*)d_in[2];
    const float* Wv = (const float*)d_in[3];
    const float* Wo = (const float*)d_in[4];
    float* out = (float*)d_out;

    float* ws = (float*)d_ws;
    float*  qb  = ws;                                   // 4M f32 (B,S,QH,DH)
    float*  kb  = qb + (size_t)cM * cQH * cDH;          // 1M f32
    float*  vb  = kb + (size_t)cM * cKVH * cDH;         // 1M f32
    ushort* xh  = (ushort*)(vb + (size_t)cM * cKVH * cDH);  // 4M bf16
    ushort* Wqh = xh  + (size_t)cM * cD;                // 1M bf16
    ushort* Wkh = Wqh + (size_t)cQH * cDH * cD;         // 256K bf16
    ushort* Wvh = Wkh + (size_t)cKVH * cDH * cD;        // 256K bf16
    ushort* Woh = Wvh + (size_t)cKVH * cDH * cD;        // 1M bf16
    ushort* abh = Woh + (size_t)cD * cQH * cDH;         // 4M bf16

    dim3 blk(256);

    // casts to bf16
    {
        const int nx  = cM * cD;
        const int nwq = cQH * cDH * cD;
        const int nwk = cKVH * cDH * cD;
        const int nwo = cD * cQH * cDH;
        cast_f32_bf16<<<(nx / 4 + 255) / 256, blk, 0, stream>>>(x, xh, nx);
        cast_f32_bf16<<<(nwq / 4 + 255) / 256, blk, 0, stream>>>(Wq, Wqh, nwq);
        cast_f32_bf16<<<(nwk / 4 + 255) / 256, blk, 0, stream>>>(Wk, Wkh, nwk);
        cast_f32_bf16<<<(nwk / 4 + 255) / 256, blk, 0, stream>>>(Wv, Wvh, nwk);
        cast_f32_bf16<<<(nwo / 4 + 255) / 256, blk, 0, stream>>>(Wo, Woh, nwo);
    }

    // QKV projections (bf16 MFMA, fp32 out)
    gemm_bf16_bt<<<dim3((cQH * cDH) / 128, cM / 128), blk, 0, stream>>>(xh, Wqh, qb, cM, cQH * cDH, cD);
    gemm_bf16_bt<<<dim3((cKVH * cDH) / 128, cM / 128), blk, 0, stream>>>(xh, Wkh, kb, cM, cKVH * cDH, cD);
    gemm_bf16_bt<<<dim3((cKVH * cDH) / 128, cM / 128), blk, 0, stream>>>(xh, Wvh, vb, cM, cKVH * cDH, cD);

    // RoPE on q and k (fp32, in place)
    {
        int totq = cM * cQH * 32;
        int totk = cM * cKVH * 32;
        rope_kernel<<<(totq + 255) / 256, blk, 0, stream>>>(qb, cQH, totq);
        rope_kernel<<<(totk + 255) / 256, blk, 0, stream>>>(kb, cKVH, totk);
    }

    // Attention (fp32 in, bf16 out)
    attn_wave_kernel<<<(cB * cQH * cS) / 4, blk, 0, stream>>>(qb, kb, vb, abh);

    // Output projection (bf16 MFMA, fp32 out)
    gemm_bf16_bt<<<dim3(cD / 128, cM / 128), blk, 0, stream>>>(abh, Woh, out, cM, cD, cD);
}